// Round 9
// baseline (182.326 us; speedup 1.0000x reference)
//
#include <hip/hip_runtime.h>
#include <hip/hip_bf16.h>

#define TQ 4096   // reference sequence length
#define LK 4096   // modality sequence length
#define QT 16     // queries per attn tile
#define NSPLIT 8  // j-split blocks per tile; x2 waves = 16 independent subs
#define NSUB (NSPLIT * 2)
#define CHJ 16    // j-chunk for per-wave w-tile
#define PB 32     // prep blocks
#define PQ (TQ / PB)

// ---------- dtype-polymorphic loads/stores (runtime sniff picks BF) ---------
template<bool BF> __device__ __forceinline__ float ld(const void* p, int i);
template<> __device__ __forceinline__ float ld<true>(const void* p, int i) {
    return __bfloat162float(((const __hip_bfloat16*)p)[i]);
}
template<> __device__ __forceinline__ float ld<false>(const void* p, int i) {
    return ((const float*)p)[i];
}
template<bool BF> __device__ __forceinline__ float2 ld2(const void* p, int i);
template<> __device__ __forceinline__ float2 ld2<false>(const void* p, int i) {
    return *(const float2*)((const float*)p + i);
}
template<> __device__ __forceinline__ float2 ld2<true>(const void* p, int i) {
    float2 r; r.x = ld<true>(p, i); r.y = ld<true>(p, i + 1); return r;
}
template<bool BF> __device__ __forceinline__ float4 ld4(const void* p, int i);
template<> __device__ __forceinline__ float4 ld4<false>(const void* p, int i) {
    return *(const float4*)((const float*)p + i);
}
template<> __device__ __forceinline__ float4 ld4<true>(const void* p, int i) {
    float4 r; r.x = ld<true>(p, i); r.y = ld<true>(p, i + 1);
    r.z = ld<true>(p, i + 2); r.w = ld<true>(p, i + 3); return r;
}
template<bool BF> __device__ __forceinline__ void st4(void* p, int i, float4 v);
template<> __device__ __forceinline__ void st4<true>(void* p, int i, float4 v) {
    __hip_bfloat16* o = (__hip_bfloat16*)p + i;
    o[0] = __float2bfloat16(v.x); o[1] = __float2bfloat16(v.y);
    o[2] = __float2bfloat16(v.z); o[3] = __float2bfloat16(v.w);
}
template<> __device__ __forceinline__ void st4<false>(void* p, int i, float4 v) {
    *(float4*)((float*)p + i) = v;
}

// ---------- dtype sniff: EVEN half-words of sorted-uniform ref_time ---------
__device__ __forceinline__ bool sniff_bf16(const void* ref_time) {
    const int lane = threadIdx.x & 63;
    bool ok = true;
    if (lane < 32) {
        float v = __bfloat162float(((const __hip_bfloat16*)ref_time)[2 * lane]);
        ok = (v >= 0.0f) && (v <= 1.0f);   // NaN fails
    }
    return __ballot(ok) == ~0ULL;
}

// ---------- binary searches ----------
__device__ int lb_int(const int* arr, int n, int key) {
    int lo = 0, hi = n;
    while (lo < hi) { int mid = (lo + hi) >> 1; if (arr[mid] < key) lo = mid + 1; else hi = mid; }
    return lo;
}
__device__ int ub_int(const int* arr, int n, int key) {
    int lo = 0, hi = n;
    while (lo < hi) { int mid = (lo + hi) >> 1; if (arr[mid] <= key) lo = mid + 1; else hi = mid; }
    return lo;
}

// ---------- prep v3 (unchanged R8): alpha/beta linear in the ref row --------
template<bool BF>
__device__ void prep_body(
    const void* ref_data, const void* ref_time, const int* ref_idx,
    const void* m1_time, const int* m1_idx, const void* m2_time, const int* m2_idx,
    const void* Wq, const void* bq,
    const void* Wk1, const void* bk1, const void* Wk2, const void* bk2,
    float* alpha1, float* beta1, float* alpha2, float* beta2,
    int* c1, int* s1, int* e1, int* c2, int* s2, int* e2)
{
    __shared__ float ut[64][4];
    __shared__ float cst[4];
    __shared__ int tabs[4][8];

    const int tid = threadIdx.x;    // 256
    const int i = tid >> 2, r = tid & 3;

    {
        const void* w = (r == 0) ? Wk1 : (r == 1) ? bk1 : (r == 2) ? Wk2 : bk2;
        const bool isA = (r & 1);
        float acc = isA ? ld<BF>(Wq, i * 128) : 0.0f;
        const float sgn = isA ? -1.0f : 1.0f;
        #pragma unroll 4
        for (int d = 1; d < 128; ++d)
            acc = fmaf(sgn * ld<BF>(Wq, i * 128 + d), ld<BF>(w, d - 1), acc);
        ut[i][r] = acc;
    }
    if (tid < 4) {
        const void* w = (tid == 0) ? Wk1 : (tid == 1) ? bk1 : (tid == 2) ? Wk2 : bk2;
        const bool isA = (tid & 1);
        float c = isA ? ld<BF>(bq, 0) : 0.0f;
        const float sgn = isA ? -1.0f : 1.0f;
        #pragma unroll 4
        for (int d = 1; d < 128; ++d)
            c = fmaf(sgn * ld<BF>(bq, d), ld<BF>(w, d - 1), c);
        c += sgn * ld<BF>(w, 127);
        cst[tid] = c;
    }
    if (tid >= 4 && tid < 36) {
        const int k = tid - 4;
        const int sid = k & 7, rest = k >> 3;
        const int modk = rest & 1, kind = rest >> 1;
        const int* arr = modk ? m2_idx : m1_idx;
        tabs[modk * 2 + kind][sid] = kind ? ub_int(arr, LK, sid) : lb_int(arr, LK, sid);
    }
    __syncthreads();

    const int q = tid & 127;
    const int t = blockIdx.x * PQ + q;
    if (tid < 128) {
        float4 acc = {cst[0], cst[1], cst[2], cst[3]};
        #pragma unroll
        for (int ii = 0; ii < 64; ii += 4) {
            const float4 rv = ld4<BF>(ref_data, t * 64 + ii);
            const float4 u0 = *(const float4*)ut[ii + 0];
            const float4 u1 = *(const float4*)ut[ii + 1];
            const float4 u2 = *(const float4*)ut[ii + 2];
            const float4 u3 = *(const float4*)ut[ii + 3];
            acc.x = fmaf(rv.x, u0.x, fmaf(rv.y, u1.x, fmaf(rv.z, u2.x, fmaf(rv.w, u3.x, acc.x))));
            acc.y = fmaf(rv.x, u0.y, fmaf(rv.y, u1.y, fmaf(rv.z, u2.y, fmaf(rv.w, u3.y, acc.y))));
            acc.z = fmaf(rv.x, u0.z, fmaf(rv.y, u1.z, fmaf(rv.z, u2.z, fmaf(rv.w, u3.z, acc.z))));
            acc.w = fmaf(rv.x, u0.w, fmaf(rv.y, u1.w, fmaf(rv.z, u2.w, fmaf(rv.w, u3.w, acc.w))));
        }
        beta1[t] = acc.x; alpha1[t] = acc.y;
        beta2[t] = acc.z; alpha2[t] = acc.w;
    } else {
        const float qt = ld<BF>(ref_time, t);
        const int g = ref_idx[t];
        int lo1 = 0, hi1 = LK, lo2 = 0, hi2 = LK;
        #pragma unroll
        for (int it = 0; it < 13; ++it) {
            const int mA = min((lo1 + hi1) >> 1, LK - 1);
            const int mB = min((lo2 + hi2) >> 1, LK - 1);
            const float v1 = ld<BF>(m1_time, mA);
            const float v2 = ld<BF>(m2_time, mB);
            if (lo1 < hi1) { if (v1 <= qt) lo1 = mA + 1; else hi1 = mA; }
            if (lo2 < hi2) { if (v2 <= qt) lo2 = mB + 1; else hi2 = mB; }
        }
        c1[t] = lo1; c2[t] = lo2;
        s1[t] = tabs[0][g]; e1[t] = tabs[1][g];
        s2[t] = tabs[2][g]; e2[t] = tabs[3][g];
    }
}

__global__ __launch_bounds__(256) void prep_kernel(
    const void* ref_data, const void* ref_time, const int* ref_idx,
    const void* m1_time, const int* m1_idx, const void* m2_time, const int* m2_idx,
    const void* Wq, const void* bq,
    const void* Wk1, const void* bk1, const void* Wk2, const void* bk2,
    float* alpha1, float* beta1, float* alpha2, float* beta2,
    int* c1, int* s1, int* e1, int* c2, int* s2, int* e2)
{
    if (sniff_bf16(ref_time))
        prep_body<true>(ref_data, ref_time, ref_idx, m1_time, m1_idx, m2_time, m2_idx,
                        Wq, bq, Wk1, bk1, Wk2, bk2,
                        alpha1, beta1, alpha2, beta2, c1, s1, e1, c2, s2, e2);
    else
        prep_body<false>(ref_data, ref_time, ref_idx, m1_time, m1_idx, m2_time, m2_idx,
                         Wq, bq, Wk1, bk1, Wk2, bk2,
                         alpha1, beta1, alpha2, beta2, c1, s1, e1, c2, s2, e2);
}

// ---------- vproj v3: 4 rows/wave (2048 waves = 8/CU), unroll 4 -------------
template<bool BF, int K, int DM>
__device__ void vproj_wave(const void* md, const void* Wv, const void* bv,
                           float* V, float* X, int rows0)
{
    const int lane = threadIdx.x & 63;
    const int cT = lane & 31;
    const int rG = lane >> 5;          // 0/1 -> rows rG*2..rG*2+1
    const int r0 = rows0 + rG * 2;
    const int c4 = cT * 4;

    const float4 bb = ld4<BF>(bv, c4);
    float4 acc[2] = {bb, bb};

    #pragma unroll 4
    for (int k = 0; k < K; k += 4) {
        const float4 w0 = ld4<BF>(Wv, (k + 0) * 128 + c4);
        const float4 w1 = ld4<BF>(Wv, (k + 1) * 128 + c4);
        const float4 w2 = ld4<BF>(Wv, (k + 2) * 128 + c4);
        const float4 w3 = ld4<BF>(Wv, (k + 3) * 128 + c4);
        float2 alo[2], ahi[2];
        #pragma unroll
        for (int r = 0; r < 2; ++r) {
            alo[r] = ld2<BF>(md, (r0 + r) * DM + k);
            ahi[r] = ld2<BF>(md, (r0 + r) * DM + k + 2);
        }
        #pragma unroll
        for (int r = 0; r < 2; ++r) {
            acc[r].x = fmaf(alo[r].x, w0.x, fmaf(alo[r].y, w1.x, fmaf(ahi[r].x, w2.x, fmaf(ahi[r].y, w3.x, acc[r].x))));
            acc[r].y = fmaf(alo[r].x, w0.y, fmaf(alo[r].y, w1.y, fmaf(ahi[r].x, w2.y, fmaf(ahi[r].y, w3.y, acc[r].y))));
            acc[r].z = fmaf(alo[r].x, w0.z, fmaf(alo[r].y, w1.z, fmaf(ahi[r].x, w2.z, fmaf(ahi[r].y, w3.z, acc[r].z))));
            acc[r].w = fmaf(alo[r].x, w0.w, fmaf(alo[r].y, w1.w, fmaf(ahi[r].x, w2.w, fmaf(ahi[r].y, w3.w, acc[r].w))));
        }
    }
    #pragma unroll
    for (int r = 0; r < 2; ++r)
        *(float4*)&V[(size_t)(r0 + r) * 128 + c4] = acc[r];
    if (rG == 0 && cT < 4)
        X[rows0 + cT] = ld<BF>(md, (rows0 + cT) * DM + DM - 1);
}

__global__ __launch_bounds__(64) void vproj_kernel(
    const void* __restrict__ ref_time,
    const void* m1_data, const void* Wv1, const void* bv1,
    const void* m2_data, const void* Wv2, const void* bv2,
    float* V1, float* V2, float* X1, float* X2)
{
    const int rows0 = blockIdx.x * 4;
    const int mod = blockIdx.y;
    const bool bf = sniff_bf16(ref_time);
    if (mod == 0) {
        if (bf) vproj_wave<true, 128, 130>(m1_data, Wv1, bv1, V1, X1, rows0);
        else    vproj_wave<false, 128, 130>(m1_data, Wv1, bv1, V1, X1, rows0);
    } else {
        if (bf) vproj_wave<true, 64, 66>(m2_data, Wv2, bv2, V2, X2, rows0);
        else    vproj_wave<false, 64, 66>(m2_data, Wv2, bv2, V2, X2, rows0);
    }
}

// ---------- attn v6: fully independent waves, no block barriers -------------
// Wave-private w-tile in LDS; cross-lane visibility within a wave needs only
// s_waitcnt lgkmcnt(0) (lockstep), not __syncthreads. 16 subs per (tile,mod),
// each wave writes its own (O,Z) partial.
__global__ __launch_bounds__(128) void attn_kernel(
    const void* __restrict__ ref_time,
    const float* __restrict__ alpha1, const float* __restrict__ beta1,
    const float* __restrict__ alpha2, const float* __restrict__ beta2,
    const int* __restrict__ c1, const int* __restrict__ s1, const int* __restrict__ e1,
    const int* __restrict__ c2, const int* __restrict__ s2, const int* __restrict__ e2,
    const float* __restrict__ V1, const float* __restrict__ V2,
    const float* __restrict__ X1, const float* __restrict__ X2,
    const void* log_tau1, const void* log_tau2,
    float* __restrict__ Opart, float* __restrict__ Zpart)
{
    __shared__ float sW[2][CHJ * QT];   // per-wave w-tile [j][q]

    const int tid = threadIdx.x;
    const int wid = tid >> 6, lane = tid & 63;
    const int t0 = blockIdx.x * QT, zb = blockIdx.y, mod = blockIdx.z;

    const bool bf = sniff_bf16(ref_time);
    const float* alpha = mod ? alpha2 : alpha1;
    const float* beta  = mod ? beta2  : beta1;
    const int* cA = mod ? c2 : c1;
    const int* sA = mod ? s2 : s1;
    const int* eA = mod ? e2 : e1;
    const float* V = mod ? V2 : V1;
    const float* X = mod ? X2 : X1;
    const void* ltp = mod ? log_tau2 : log_tau1;
    const float scale = __expf(-(bf ? ld<true>(ltp, 0) : ld<false>(ltp, 0)));

    const int q = lane & 15;
    const int t = t0 + q;
    int s = sA[t], e = eA[t];
    const int c = cA[t];
    if (s == e) { s = 0; e = LK; }        // fully-masked fallback
    const int cm = min(c, e);             // causal&matched: [s, cm)
    const float al = alpha[t], be = beta[t];

    // tile union range via wave reduce (empty queries excluded)
    int es = (cm > s) ? s : 0x7fffffff;
    int ec = (cm > s) ? cm : 0;
    #pragma unroll
    for (int o = 1; o < 64; o <<= 1) {
        es = min(es, __shfl_xor(es, o));
        ec = max(ec, __shfl_xor(ec, o));
    }
    int jlo = es, jhi = ec;
    if (jlo > jhi) { jlo = 0; jhi = 0; }
    const int W = jhi - jlo;
    const int chunk = (W + NSUB - 1) / NSUB;
    const int sub = zb * 2 + wid;
    const int lo = jlo + sub * chunk;
    int hi = min(jhi, lo + chunk); if (hi < lo) hi = lo;

    const int cT = lane & 31, qG = lane >> 5;
    const int jj = lane >> 4;               // 0..3 -> j-slots jj*4..jj*4+3
    float4 acc[8] = {{0,0,0,0},{0,0,0,0},{0,0,0,0},{0,0,0,0},
                     {0,0,0,0},{0,0,0,0},{0,0,0,0},{0,0,0,0}};
    float zacc = 0.0f;
    float* myW = sW[wid];
    const float4* __restrict__ Vg = (const float4*)V;

    for (int base = lo; base < hi; base += CHJ) {
        const int jm = min(CHJ, hi - base);
        // drain prior chunk's ds_reads before overwriting the tile
        __asm__ volatile("s_waitcnt lgkmcnt(0)" ::: "memory");
        #pragma unroll
        for (int p = 0; p < 4; ++p) {
            const int jr = jj * 4 + p;      // 0..15, full tile coverage
            const int j = base + jr;
            const bool ok = (jr < jm) && (j >= s) && (j < cm);
            const float x = X[min(j, LK - 1)];
            const float qk = fmaf(-be, x, al);
            const float w = ok ? __expf(-(qk * qk) * scale) : 0.0f;
            myW[jr * QT + q] = w;
            zacc += w;
        }
        // make this wave's LDS writes visible to all its lanes
        __asm__ volatile("s_waitcnt lgkmcnt(0)" ::: "memory");
        #pragma unroll 4
        for (int j = 0; j < jm; ++j) {
            const float4 v = Vg[(base + j) * 32 + cT];
            const float4* wv = (const float4*)&myW[j * QT + qG * 8];
            const float4 wA = wv[0], wB = wv[1];
            acc[0].x = fmaf(wA.x, v.x, acc[0].x); acc[0].y = fmaf(wA.x, v.y, acc[0].y);
            acc[0].z = fmaf(wA.x, v.z, acc[0].z); acc[0].w = fmaf(wA.x, v.w, acc[0].w);
            acc[1].x = fmaf(wA.y, v.x, acc[1].x); acc[1].y = fmaf(wA.y, v.y, acc[1].y);
            acc[1].z = fmaf(wA.y, v.z, acc[1].z); acc[1].w = fmaf(wA.y, v.w, acc[1].w);
            acc[2].x = fmaf(wA.z, v.x, acc[2].x); acc[2].y = fmaf(wA.z, v.y, acc[2].y);
            acc[2].z = fmaf(wA.z, v.z, acc[2].z); acc[2].w = fmaf(wA.z, v.w, acc[2].w);
            acc[3].x = fmaf(wA.w, v.x, acc[3].x); acc[3].y = fmaf(wA.w, v.y, acc[3].y);
            acc[3].z = fmaf(wA.w, v.z, acc[3].z); acc[3].w = fmaf(wA.w, v.w, acc[3].w);
            acc[4].x = fmaf(wB.x, v.x, acc[4].x); acc[4].y = fmaf(wB.x, v.y, acc[4].y);
            acc[4].z = fmaf(wB.x, v.z, acc[4].z); acc[4].w = fmaf(wB.x, v.w, acc[4].w);
            acc[5].x = fmaf(wB.y, v.x, acc[5].x); acc[5].y = fmaf(wB.y, v.y, acc[5].y);
            acc[5].z = fmaf(wB.y, v.z, acc[5].z); acc[5].w = fmaf(wB.y, v.w, acc[5].w);
            acc[6].x = fmaf(wB.z, v.x, acc[6].x); acc[6].y = fmaf(wB.z, v.y, acc[6].y);
            acc[6].z = fmaf(wB.z, v.z, acc[6].z); acc[6].w = fmaf(wB.z, v.w, acc[6].w);
            acc[7].x = fmaf(wB.w, v.x, acc[7].x); acc[7].y = fmaf(wB.w, v.y, acc[7].y);
            acc[7].z = fmaf(wB.w, v.z, acc[7].z); acc[7].w = fmaf(wB.w, v.w, acc[7].w);
        }
    }

    // z: reduce over the 4 lanes sharing this q
    float z = zacc;
    z += __shfl_xor(z, 16);
    z += __shfl_xor(z, 32);

    const int part = sub * 2 + mod;       // 0..31
    float4* Og = (float4*)Opart;
    #pragma unroll
    for (int r = 0; r < 8; ++r)
        Og[((size_t)(part << 12) + (t0 + qG * 8 + r)) * 32 + cT] = acc[r];
    if (lane < 16) Zpart[(part << 12) + t0 + lane] = z;
}

// ---------- finish: merge NSUB partials + n_nc, normalize, store ------------
__global__ __launch_bounds__(256) void finish_kernel(
    const void* __restrict__ ref_time,
    const int* __restrict__ c1, const int* __restrict__ s1, const int* __restrict__ e1,
    const int* __restrict__ c2, const int* __restrict__ s2, const int* __restrict__ e2,
    const float* __restrict__ Zpart, const float* __restrict__ Opart,
    void* __restrict__ out)
{
    const bool bf = sniff_bf16(ref_time);
    const int idx = blockIdx.x * 256 + threadIdx.x;
    const int t = idx >> 6;
    const int rem = idx & 63;
    const int mod = rem >> 5;
    const int c4 = rem & 31;

    const int* cA = mod ? c2 : c1;
    const int* sA = mod ? s2 : s1;
    const int* eA = mod ? e2 : e1;
    int s = sA[t], e = eA[t];
    const int c = cA[t];
    if (s == e) { s = 0; e = LK; }
    const int nnc = (e > c) ? (e - max(s, c)) : 0;

    float Z = (float)nnc;
    float4 o = {0, 0, 0, 0};
    const float4* Og = (const float4*)Opart;
    #pragma unroll
    for (int zi = 0; zi < NSUB; ++zi) {
        const int part = zi * 2 + mod;
        Z += Zpart[(part << 12) + t];
        const float4 p = Og[((size_t)(part << 12) + t) * 32 + c4];
        o.x += p.x; o.y += p.y; o.z += p.z; o.w += p.w;
    }
    const float inv = 1.0f / fmaxf(Z, 1.0e-20f);
    o.x *= inv; o.y *= inv; o.z *= inv; o.w *= inv;
    if (bf) st4<true>(out, t * 256 + mod * 128 + c4 * 4, o);
    else    st4<false>(out, t * 256 + mod * 128 + c4 * 4, o);
}

extern "C" void kernel_launch(void* const* d_in, const int* in_sizes, int n_in,
                              void* d_out, int out_size, void* d_ws, size_t ws_size,
                              hipStream_t stream)
{
    const void* ref_data = d_in[0];
    const void* ref_time = d_in[1];
    const int*  ref_idx  = (const int*)d_in[2];
    const void* m1_data  = d_in[3];
    const void* m1_time  = d_in[4];
    const int*  m1_idx   = (const int*)d_in[5];
    const void* m2_data  = d_in[6];
    const void* m2_time  = d_in[7];
    const int*  m2_idx   = (const int*)d_in[8];
    const void* Wq  = d_in[9];
    const void* bq  = d_in[10];
    const void* Wk1 = d_in[11];
    const void* bk1 = d_in[12];
    const void* Wv1 = d_in[13];
    const void* bv1 = d_in[14];
    const void* Wk2 = d_in[15];
    const void* bk2 = d_in[16];
    const void* Wv2 = d_in[17];
    const void* bv2 = d_in[18];
    const void* log_tau1 = d_in[19];
    const void* log_tau2 = d_in[20];

    float* ws = (float*)d_ws;
    float* alpha1 = ws + 0 * TQ;
    float* beta1  = ws + 1 * TQ;
    float* alpha2 = ws + 2 * TQ;
    float* beta2  = ws + 3 * TQ;
    int*   c1 = (int*)(ws + 4 * TQ);
    int*   c2 = (int*)(ws + 5 * TQ);
    int*   s1 = (int*)(ws + 6 * TQ);
    int*   e1 = (int*)(ws + 7 * TQ);
    int*   s2 = (int*)(ws + 8 * TQ);
    int*   e2 = (int*)(ws + 9 * TQ);
    float* X1 = ws + 10 * TQ;
    float* X2 = ws + 11 * TQ;
    float* V1 = ws + 12 * TQ;                      // LK*128 floats
    float* V2 = V1 + (size_t)LK * 128;
    float* Zpart = V2 + (size_t)LK * 128;          // 32*TQ floats
    float* Opart = Zpart + 32 * TQ;                // 32*TQ*128 floats (67 MB)

    prep_kernel<<<dim3(PB), dim3(256), 0, stream>>>(
        ref_data, ref_time, ref_idx, m1_time, m1_idx, m2_time, m2_idx,
        Wq, bq, Wk1, bk1, Wk2, bk2,
        alpha1, beta1, alpha2, beta2, c1, s1, e1, c2, s2, e2);

    vproj_kernel<<<dim3(LK / 4, 2), dim3(64), 0, stream>>>(
        ref_time, m1_data, Wv1, bv1, m2_data, Wv2, bv2, V1, V2, X1, X2);

    attn_kernel<<<dim3(TQ / QT, NSPLIT, 2), dim3(128), 0, stream>>>(
        ref_time, alpha1, beta1, alpha2, beta2, c1, s1, e1, c2, s2, e2,
        V1, V2, X1, X2, log_tau1, log_tau2, Opart, Zpart);

    finish_kernel<<<dim3(TQ * 2 * 32 / 256), dim3(256), 0, stream>>>(
        ref_time, c1, s1, e1, c2, s2, e2, Zpart, Opart, (void*)d_out);
}

// Round 10
// 164.109 us; speedup vs baseline: 1.1110x; 1.1110x over previous
//
#include <hip/hip_runtime.h>
#include <hip/hip_bf16.h>

#define TQ 4096   // reference sequence length
#define LK 4096   // modality sequence length
#define QT 16     // queries per attn tile
#define NSPLIT 4  // j-split blocks per (tile,mod); x2 waves = 8 sub-slices
#define CHJ 16    // j-chunk for per-wave w-tile
#define PB 32     // prep blocks
#define PQ (TQ / PB)
#define VPB 512   // vproj blocks (256 per modality, 16 rows each)

// ---------- dtype-polymorphic loads/stores (runtime sniff picks BF) ---------
template<bool BF> __device__ __forceinline__ float ld(const void* p, int i);
template<> __device__ __forceinline__ float ld<true>(const void* p, int i) {
    return __bfloat162float(((const __hip_bfloat16*)p)[i]);
}
template<> __device__ __forceinline__ float ld<false>(const void* p, int i) {
    return ((const float*)p)[i];
}
template<bool BF> __device__ __forceinline__ float2 ld2(const void* p, int i);
template<> __device__ __forceinline__ float2 ld2<false>(const void* p, int i) {
    return *(const float2*)((const float*)p + i);
}
template<> __device__ __forceinline__ float2 ld2<true>(const void* p, int i) {
    float2 r; r.x = ld<true>(p, i); r.y = ld<true>(p, i + 1); return r;
}
template<bool BF> __device__ __forceinline__ float4 ld4(const void* p, int i);
template<> __device__ __forceinline__ float4 ld4<false>(const void* p, int i) {
    return *(const float4*)((const float*)p + i);
}
template<> __device__ __forceinline__ float4 ld4<true>(const void* p, int i) {
    float4 r; r.x = ld<true>(p, i); r.y = ld<true>(p, i + 1);
    r.z = ld<true>(p, i + 2); r.w = ld<true>(p, i + 3); return r;
}
template<bool BF> __device__ __forceinline__ void st4(void* p, int i, float4 v);
template<> __device__ __forceinline__ void st4<true>(void* p, int i, float4 v) {
    __hip_bfloat16* o = (__hip_bfloat16*)p + i;
    o[0] = __float2bfloat16(v.x); o[1] = __float2bfloat16(v.y);
    o[2] = __float2bfloat16(v.z); o[3] = __float2bfloat16(v.w);
}
template<> __device__ __forceinline__ void st4<false>(void* p, int i, float4 v) {
    *(float4*)((float*)p + i) = v;
}

// ---------- dtype sniff: EVEN half-words of sorted-uniform ref_time ---------
__device__ __forceinline__ bool sniff_bf16(const void* ref_time) {
    const int lane = threadIdx.x & 63;
    bool ok = true;
    if (lane < 32) {
        float v = __bfloat162float(((const __hip_bfloat16*)ref_time)[2 * lane]);
        ok = (v >= 0.0f) && (v <= 1.0f);   // NaN fails
    }
    return __ballot(ok) == ~0ULL;
}

// ---------- binary searches ----------
__device__ int lb_int(const int* arr, int n, int key) {
    int lo = 0, hi = n;
    while (lo < hi) { int mid = (lo + hi) >> 1; if (arr[mid] < key) lo = mid + 1; else hi = mid; }
    return lo;
}
__device__ int ub_int(const int* arr, int n, int key) {
    int lo = 0, hi = n;
    while (lo < hi) { int mid = (lo + hi) >> 1; if (arr[mid] <= key) lo = mid + 1; else hi = mid; }
    return lo;
}

// ---------- prep part: alpha/beta linear in the ref row ---------------------
template<bool BF>
__device__ void prep_part(
    const void* ref_data, const void* ref_time, const int* ref_idx,
    const void* m1_time, const int* m1_idx, const void* m2_time, const int* m2_idx,
    const void* Wq, const void* bq,
    const void* Wk1, const void* bk1, const void* Wk2, const void* bk2,
    float* alpha1, float* beta1, float* alpha2, float* beta2,
    int* c1, int* s1, int* e1, int* c2, int* s2, int* e2)
{
    __shared__ float ut[64][4];
    __shared__ float cst[4];
    __shared__ int tabs[4][8];

    const int tid = threadIdx.x;    // 256
    const int i = tid >> 2, r = tid & 3;

    {
        const void* w = (r == 0) ? Wk1 : (r == 1) ? bk1 : (r == 2) ? Wk2 : bk2;
        const bool isA = (r & 1);
        float acc = isA ? ld<BF>(Wq, i * 128) : 0.0f;
        const float sgn = isA ? -1.0f : 1.0f;
        #pragma unroll 4
        for (int d = 1; d < 128; ++d)
            acc = fmaf(sgn * ld<BF>(Wq, i * 128 + d), ld<BF>(w, d - 1), acc);
        ut[i][r] = acc;
    }
    if (tid < 4) {
        const void* w = (tid == 0) ? Wk1 : (tid == 1) ? bk1 : (tid == 2) ? Wk2 : bk2;
        const bool isA = (tid & 1);
        float c = isA ? ld<BF>(bq, 0) : 0.0f;
        const float sgn = isA ? -1.0f : 1.0f;
        #pragma unroll 4
        for (int d = 1; d < 128; ++d)
            c = fmaf(sgn * ld<BF>(bq, d), ld<BF>(w, d - 1), c);
        c += sgn * ld<BF>(w, 127);
        cst[tid] = c;
    }
    if (tid >= 4 && tid < 36) {
        const int k = tid - 4;
        const int sid = k & 7, rest = k >> 3;
        const int modk = rest & 1, kind = rest >> 1;
        const int* arr = modk ? m2_idx : m1_idx;
        tabs[modk * 2 + kind][sid] = kind ? ub_int(arr, LK, sid) : lb_int(arr, LK, sid);
    }
    __syncthreads();

    const int q = tid & 127;
    const int t = blockIdx.x * PQ + q;
    if (tid < 128) {
        float4 acc = {cst[0], cst[1], cst[2], cst[3]};
        #pragma unroll
        for (int ii = 0; ii < 64; ii += 4) {
            const float4 rv = ld4<BF>(ref_data, t * 64 + ii);
            const float4 u0 = *(const float4*)ut[ii + 0];
            const float4 u1 = *(const float4*)ut[ii + 1];
            const float4 u2 = *(const float4*)ut[ii + 2];
            const float4 u3 = *(const float4*)ut[ii + 3];
            acc.x = fmaf(rv.x, u0.x, fmaf(rv.y, u1.x, fmaf(rv.z, u2.x, fmaf(rv.w, u3.x, acc.x))));
            acc.y = fmaf(rv.x, u0.y, fmaf(rv.y, u1.y, fmaf(rv.z, u2.y, fmaf(rv.w, u3.y, acc.y))));
            acc.z = fmaf(rv.x, u0.z, fmaf(rv.y, u1.z, fmaf(rv.z, u2.z, fmaf(rv.w, u3.z, acc.z))));
            acc.w = fmaf(rv.x, u0.w, fmaf(rv.y, u1.w, fmaf(rv.z, u2.w, fmaf(rv.w, u3.w, acc.w))));
        }
        beta1[t] = acc.x; alpha1[t] = acc.y;
        beta2[t] = acc.z; alpha2[t] = acc.w;
    } else {
        const float qt = ld<BF>(ref_time, t);
        const int g = ref_idx[t];
        int lo1 = 0, hi1 = LK, lo2 = 0, hi2 = LK;
        #pragma unroll
        for (int it = 0; it < 13; ++it) {
            const int mA = min((lo1 + hi1) >> 1, LK - 1);
            const int mB = min((lo2 + hi2) >> 1, LK - 1);
            const float v1 = ld<BF>(m1_time, mA);
            const float v2 = ld<BF>(m2_time, mB);
            if (lo1 < hi1) { if (v1 <= qt) lo1 = mA + 1; else hi1 = mA; }
            if (lo2 < hi2) { if (v2 <= qt) lo2 = mB + 1; else hi2 = mB; }
        }
        c1[t] = lo1; c2[t] = lo2;
        s1[t] = tabs[0][g]; e1[t] = tabs[1][g];
        s2[t] = tabs[2][g]; e2[t] = tabs[3][g];
    }
}

// ---------- vproj part: one wave per 4 rows, register-tiled, no LDS ---------
template<bool BF, int K, int DM>
__device__ void vproj_wave(const void* md, const void* Wv, const void* bv,
                           float* V, float* X, int rows0)
{
    const int lane = threadIdx.x & 63;
    const int cT = lane & 31;
    const int rG = lane >> 5;          // 0/1 -> rows rG*2..rG*2+1
    const int r0 = rows0 + rG * 2;
    const int c4 = cT * 4;

    const float4 bb = ld4<BF>(bv, c4);
    float4 acc[2] = {bb, bb};

    #pragma unroll 4
    for (int k = 0; k < K; k += 4) {
        const float4 w0 = ld4<BF>(Wv, (k + 0) * 128 + c4);
        const float4 w1 = ld4<BF>(Wv, (k + 1) * 128 + c4);
        const float4 w2 = ld4<BF>(Wv, (k + 2) * 128 + c4);
        const float4 w3 = ld4<BF>(Wv, (k + 3) * 128 + c4);
        float2 alo[2], ahi[2];
        #pragma unroll
        for (int r = 0; r < 2; ++r) {
            alo[r] = ld2<BF>(md, (r0 + r) * DM + k);
            ahi[r] = ld2<BF>(md, (r0 + r) * DM + k + 2);
        }
        #pragma unroll
        for (int r = 0; r < 2; ++r) {
            acc[r].x = fmaf(alo[r].x, w0.x, fmaf(alo[r].y, w1.x, fmaf(ahi[r].x, w2.x, fmaf(ahi[r].y, w3.x, acc[r].x))));
            acc[r].y = fmaf(alo[r].x, w0.y, fmaf(alo[r].y, w1.y, fmaf(ahi[r].x, w2.y, fmaf(ahi[r].y, w3.y, acc[r].y))));
            acc[r].z = fmaf(alo[r].x, w0.z, fmaf(alo[r].y, w1.z, fmaf(ahi[r].x, w2.z, fmaf(ahi[r].y, w3.z, acc[r].z))));
            acc[r].w = fmaf(alo[r].x, w0.w, fmaf(alo[r].y, w1.w, fmaf(ahi[r].x, w2.w, fmaf(ahi[r].y, w3.w, acc[r].w))));
        }
    }
    #pragma unroll
    for (int r = 0; r < 2; ++r)
        *(float4*)&V[(size_t)(r0 + r) * 128 + c4] = acc[r];
    if (rG == 0 && cT < 4)
        X[rows0 + cT] = ld<BF>(md, (rows0 + cT) * DM + DM - 1);
}

// ---------- fused prep+vproj (one launch) -----------------------------------
template<bool BF>
__device__ void pv_body(
    const void* ref_data, const void* ref_time, const int* ref_idx,
    const void* m1_data, const void* m1_time, const int* m1_idx,
    const void* m2_data, const void* m2_time, const int* m2_idx,
    const void* Wq, const void* bq,
    const void* Wk1, const void* bk1, const void* Wk2, const void* bk2,
    const void* Wv1, const void* bv1, const void* Wv2, const void* bv2,
    float* alpha1, float* beta1, float* alpha2, float* beta2,
    int* c1, int* s1, int* e1, int* c2, int* s2, int* e2,
    float* V1, float* V2, float* X1, float* X2)
{
    if (blockIdx.x < PB) {
        prep_part<BF>(ref_data, ref_time, ref_idx, m1_time, m1_idx, m2_time, m2_idx,
                      Wq, bq, Wk1, bk1, Wk2, bk2,
                      alpha1, beta1, alpha2, beta2, c1, s1, e1, c2, s2, e2);
    } else {
        const int vb = blockIdx.x - PB;          // 0..VPB-1
        const int mod = vb >> 8;                 // 256 blocks per modality
        const int wid = threadIdx.x >> 6;        // 4 waves x 4 rows = 16 rows/block
        const int rows0 = (vb & 255) * 16 + wid * 4;
        if (mod == 0) vproj_wave<BF, 128, 130>(m1_data, Wv1, bv1, V1, X1, rows0);
        else          vproj_wave<BF, 64, 66>(m2_data, Wv2, bv2, V2, X2, rows0);
    }
}

__global__ __launch_bounds__(256) void pv_kernel(
    const void* ref_data, const void* ref_time, const int* ref_idx,
    const void* m1_data, const void* m1_time, const int* m1_idx,
    const void* m2_data, const void* m2_time, const int* m2_idx,
    const void* Wq, const void* bq,
    const void* Wk1, const void* bk1, const void* Wk2, const void* bk2,
    const void* Wv1, const void* bv1, const void* Wv2, const void* bv2,
    float* alpha1, float* beta1, float* alpha2, float* beta2,
    int* c1, int* s1, int* e1, int* c2, int* s2, int* e2,
    float* V1, float* V2, float* X1, float* X2)
{
    if (sniff_bf16(ref_time))
        pv_body<true>(ref_data, ref_time, ref_idx, m1_data, m1_time, m1_idx,
                      m2_data, m2_time, m2_idx, Wq, bq, Wk1, bk1, Wk2, bk2,
                      Wv1, bv1, Wv2, bv2, alpha1, beta1, alpha2, beta2,
                      c1, s1, e1, c2, s2, e2, V1, V2, X1, X2);
    else
        pv_body<false>(ref_data, ref_time, ref_idx, m1_data, m1_time, m1_idx,
                       m2_data, m2_time, m2_idx, Wq, bq, Wk1, bk1, Wk2, bk2,
                       Wv1, bv1, Wv2, bv2, alpha1, beta1, alpha2, beta2,
                       c1, s1, e1, c2, s2, e2, V1, V2, X1, X2);
}

// ---------- attn v7: barrier-free chunk loop (per-wave w-tile + lgkmcnt),
// 2 waves/block on adjacent j-sub-slices, single end-merge barrier. ----------
__global__ __launch_bounds__(128) void attn_kernel(
    const void* __restrict__ ref_time,
    const float* __restrict__ alpha1, const float* __restrict__ beta1,
    const float* __restrict__ alpha2, const float* __restrict__ beta2,
    const int* __restrict__ c1, const int* __restrict__ s1, const int* __restrict__ e1,
    const int* __restrict__ c2, const int* __restrict__ s2, const int* __restrict__ e2,
    const float* __restrict__ V1, const float* __restrict__ V2,
    const float* __restrict__ X1, const float* __restrict__ X2,
    const void* log_tau1, const void* log_tau2,
    float* __restrict__ Opart, float* __restrict__ Zpart)
{
    __shared__ float sW[2][CHJ * QT];   // per-wave w-tile [j][q]
    __shared__ float sO[QT * 128];      // cross-wave O merge
    __shared__ float sZm[QT];

    const int tid = threadIdx.x;
    const int wid = tid >> 6, lane = tid & 63;
    const int t0 = blockIdx.x * QT, zb = blockIdx.y, mod = blockIdx.z;

    const bool bf = sniff_bf16(ref_time);
    const float* alpha = mod ? alpha2 : alpha1;
    const float* beta  = mod ? beta2  : beta1;
    const int* cA = mod ? c2 : c1;
    const int* sA = mod ? s2 : s1;
    const int* eA = mod ? e2 : e1;
    const float* V = mod ? V2 : V1;
    const float* X = mod ? X2 : X1;
    const void* ltp = mod ? log_tau2 : log_tau1;
    const float scale = __expf(-(bf ? ld<true>(ltp, 0) : ld<false>(ltp, 0)));

    const int q = lane & 15;
    const int t = t0 + q;
    int s = sA[t], e = eA[t];
    const int c = cA[t];
    if (s == e) { s = 0; e = LK; }        // fully-masked fallback
    const int cm = min(c, e);             // causal&matched: [s, cm)
    const float al = alpha[t], be = beta[t];

    // tile union range via wave reduce (empty queries excluded)
    int es = (cm > s) ? s : 0x7fffffff;
    int ec = (cm > s) ? cm : 0;
    #pragma unroll
    for (int o = 1; o < 64; o <<= 1) {
        es = min(es, __shfl_xor(es, o));
        ec = max(ec, __shfl_xor(ec, o));
    }
    int jlo = es, jhi = ec;
    if (jlo > jhi) { jlo = 0; jhi = 0; }
    const int W = jhi - jlo;
    const int chunk = (W + NSPLIT * 2 - 1) / (NSPLIT * 2);
    const int sub = zb * 2 + wid;
    const int lo = jlo + sub * chunk;
    int hi = min(jhi, lo + chunk); if (hi < lo) hi = lo;

    const int cT = lane & 31, qG = lane >> 5;
    const int jj = lane >> 4;               // 0..3 -> j-slots jj*4..jj*4+3
    float4 acc[8] = {{0,0,0,0},{0,0,0,0},{0,0,0,0},{0,0,0,0},
                     {0,0,0,0},{0,0,0,0},{0,0,0,0},{0,0,0,0}};
    float zacc = 0.0f;
    float* myW = sW[wid];
    const float4* __restrict__ Vg = (const float4*)V;

    for (int base = lo; base < hi; base += CHJ) {
        const int jm = min(CHJ, hi - base);
        // drain prior chunk's ds_reads before overwriting this wave's tile
        __asm__ volatile("s_waitcnt lgkmcnt(0)" ::: "memory");
        #pragma unroll
        for (int p = 0; p < 4; ++p) {
            const int jr = jj * 4 + p;      // 0..15, full tile coverage
            const int j = base + jr;
            const bool ok = (jr < jm) && (j >= s) && (j < cm);
            const float x = X[min(j, LK - 1)];
            const float qk = fmaf(-be, x, al);
            const float w = ok ? __expf(-(qk * qk) * scale) : 0.0f;
            myW[jr * QT + q] = w;
            zacc += w;
        }
        // make this wave's LDS writes visible to all its lanes
        __asm__ volatile("s_waitcnt lgkmcnt(0)" ::: "memory");
        #pragma unroll 4
        for (int j = 0; j < jm; ++j) {
            const float4 v = Vg[(base + j) * 32 + cT];
            const float4* wv = (const float4*)&myW[j * QT + qG * 8];
            const float4 wA = wv[0], wB = wv[1];
            acc[0].x = fmaf(wA.x, v.x, acc[0].x); acc[0].y = fmaf(wA.x, v.y, acc[0].y);
            acc[0].z = fmaf(wA.x, v.z, acc[0].z); acc[0].w = fmaf(wA.x, v.w, acc[0].w);
            acc[1].x = fmaf(wA.y, v.x, acc[1].x); acc[1].y = fmaf(wA.y, v.y, acc[1].y);
            acc[1].z = fmaf(wA.y, v.z, acc[1].z); acc[1].w = fmaf(wA.y, v.w, acc[1].w);
            acc[2].x = fmaf(wA.z, v.x, acc[2].x); acc[2].y = fmaf(wA.z, v.y, acc[2].y);
            acc[2].z = fmaf(wA.z, v.z, acc[2].z); acc[2].w = fmaf(wA.z, v.w, acc[2].w);
            acc[3].x = fmaf(wA.w, v.x, acc[3].x); acc[3].y = fmaf(wA.w, v.y, acc[3].y);
            acc[3].z = fmaf(wA.w, v.z, acc[3].z); acc[3].w = fmaf(wA.w, v.w, acc[3].w);
            acc[4].x = fmaf(wB.x, v.x, acc[4].x); acc[4].y = fmaf(wB.x, v.y, acc[4].y);
            acc[4].z = fmaf(wB.x, v.z, acc[4].z); acc[4].w = fmaf(wB.x, v.w, acc[4].w);
            acc[5].x = fmaf(wB.y, v.x, acc[5].x); acc[5].y = fmaf(wB.y, v.y, acc[5].y);
            acc[5].z = fmaf(wB.y, v.z, acc[5].z); acc[5].w = fmaf(wB.y, v.w, acc[5].w);
            acc[6].x = fmaf(wB.z, v.x, acc[6].x); acc[6].y = fmaf(wB.z, v.y, acc[6].y);
            acc[6].z = fmaf(wB.z, v.z, acc[6].z); acc[6].w = fmaf(wB.z, v.w, acc[6].w);
            acc[7].x = fmaf(wB.w, v.x, acc[7].x); acc[7].y = fmaf(wB.w, v.y, acc[7].y);
            acc[7].z = fmaf(wB.w, v.z, acc[7].z); acc[7].w = fmaf(wB.w, v.w, acc[7].w);
        }
    }

    // z: reduce over the 4 lanes sharing this q
    float z = zacc;
    z += __shfl_xor(z, 16);
    z += __shfl_xor(z, 32);

    // cross-wave merge: wave0 deposits, single barrier, wave1 adds + stores.
    const int part = zb * 2 + mod;        // 0..7
    if (wid == 0) {
        #pragma unroll
        for (int r = 0; r < 8; ++r)
            *(float4*)&sO[(qG * 8 + r) * 128 + cT * 4] = acc[r];
        if (lane < 16) sZm[lane] = z;
    }
    __syncthreads();
    if (wid == 1) {
        float4* Og = (float4*)Opart;
        #pragma unroll
        for (int r = 0; r < 8; ++r) {
            const float4 o0 = *(const float4*)&sO[(qG * 8 + r) * 128 + cT * 4];
            float4 o = acc[r];
            o.x += o0.x; o.y += o0.y; o.z += o0.z; o.w += o0.w;
            Og[((size_t)(part << 12) + (t0 + qG * 8 + r)) * 32 + cT] = o;
        }
        if (lane < 16) Zpart[(part << 12) + t0 + lane] = z + sZm[lane];
    }
}

// ---------- finish: merge NSPLIT partials + n_nc, normalize, store ----------
__global__ __launch_bounds__(256) void finish_kernel(
    const void* __restrict__ ref_time,
    const int* __restrict__ c1, const int* __restrict__ s1, const int* __restrict__ e1,
    const int* __restrict__ c2, const int* __restrict__ s2, const int* __restrict__ e2,
    const float* __restrict__ Zpart, const float* __restrict__ Opart,
    void* __restrict__ out)
{
    const bool bf = sniff_bf16(ref_time);
    const int idx = blockIdx.x * 256 + threadIdx.x;
    const int t = idx >> 6;
    const int rem = idx & 63;
    const int mod = rem >> 5;
    const int c4 = rem & 31;

    const int* cA = mod ? c2 : c1;
    const int* sA = mod ? s2 : s1;
    const int* eA = mod ? e2 : e1;
    int s = sA[t], e = eA[t];
    const int c = cA[t];
    if (s == e) { s = 0; e = LK; }
    const int nnc = (e > c) ? (e - max(s, c)) : 0;

    float Z = (float)nnc;
    float4 o = {0, 0, 0, 0};
    const float4* Og = (const float4*)Opart;
    #pragma unroll
    for (int zb = 0; zb < NSPLIT; ++zb) {
        const int part = zb * 2 + mod;
        Z += Zpart[(part << 12) + t];
        const float4 p = Og[((size_t)(part << 12) + t) * 32 + c4];
        o.x += p.x; o.y += p.y; o.z += p.z; o.w += p.w;
    }
    const float inv = 1.0f / fmaxf(Z, 1.0e-20f);
    o.x *= inv; o.y *= inv; o.z *= inv; o.w *= inv;
    if (bf) st4<true>(out, t * 256 + mod * 128 + c4 * 4, o);
    else    st4<false>(out, t * 256 + mod * 128 + c4 * 4, o);
}

extern "C" void kernel_launch(void* const* d_in, const int* in_sizes, int n_in,
                              void* d_out, int out_size, void* d_ws, size_t ws_size,
                              hipStream_t stream)
{
    const void* ref_data = d_in[0];
    const void* ref_time = d_in[1];
    const int*  ref_idx  = (const int*)d_in[2];
    const void* m1_data  = d_in[3];
    const void* m1_time  = d_in[4];
    const int*  m1_idx   = (const int*)d_in[5];
    const void* m2_data  = d_in[6];
    const void* m2_time  = d_in[7];
    const int*  m2_idx   = (const int*)d_in[8];
    const void* Wq  = d_in[9];
    const void* bq  = d_in[10];
    const void* Wk1 = d_in[11];
    const void* bk1 = d_in[12];
    const void* Wv1 = d_in[13];
    const void* bv1 = d_in[14];
    const void* Wk2 = d_in[15];
    const void* bk2 = d_in[16];
    const void* Wv2 = d_in[17];
    const void* bv2 = d_in[18];
    const void* log_tau1 = d_in[19];
    const void* log_tau2 = d_in[20];

    float* ws = (float*)d_ws;
    float* alpha1 = ws + 0 * TQ;
    float* beta1  = ws + 1 * TQ;
    float* alpha2 = ws + 2 * TQ;
    float* beta2  = ws + 3 * TQ;
    int*   c1 = (int*)(ws + 4 * TQ);
    int*   c2 = (int*)(ws + 5 * TQ);
    int*   s1 = (int*)(ws + 6 * TQ);
    int*   e1 = (int*)(ws + 7 * TQ);
    int*   s2 = (int*)(ws + 8 * TQ);
    int*   e2 = (int*)(ws + 9 * TQ);
    float* X1 = ws + 10 * TQ;
    float* X2 = ws + 11 * TQ;
    float* V1 = ws + 12 * TQ;                      // LK*128 floats
    float* V2 = V1 + (size_t)LK * 128;
    float* Zpart = V2 + (size_t)LK * 128;          // 8*TQ floats
    float* Opart = Zpart + 8 * TQ;                 // 8*TQ*128 floats (16.8 MB)

    pv_kernel<<<dim3(PB + VPB), dim3(256), 0, stream>>>(
        ref_data, ref_time, ref_idx, m1_data, m1_time, m1_idx,
        m2_data, m2_time, m2_idx, Wq, bq, Wk1, bk1, Wk2, bk2,
        Wv1, bv1, Wv2, bv2, alpha1, beta1, alpha2, beta2,
        c1, s1, e1, c2, s2, e2, V1, V2, X1, X2);

    attn_kernel<<<dim3(TQ / QT, NSPLIT, 2), dim3(128), 0, stream>>>(
        ref_time, alpha1, beta1, alpha2, beta2, c1, s1, e1, c2, s2, e2,
        V1, V2, X1, X2, log_tau1, log_tau2, Opart, Zpart);

    finish_kernel<<<dim3(TQ * 2 * 32 / 256), dim3(256), 0, stream>>>(
        ref_time, c1, s1, e1, c2, s2, e2, Zpart, Opart, (void*)d_out);
}

// Round 11
// 156.085 us; speedup vs baseline: 1.1681x; 1.0514x over previous
//
#include <hip/hip_runtime.h>
#include <hip/hip_bf16.h>

#define TQ 4096   // reference sequence length
#define LK 4096   // modality sequence length
#define QT 16     // queries per attn tile
#define NW 8      // waves per attn block (one sub-slice each)
#define CHJ 16    // j-chunk for per-wave w-tile
#define PB 32     // prep blocks
#define PQ (TQ / PB)
#define VPB 512   // vproj blocks (256 per modality, 16 rows each)

// ---------- dtype-polymorphic loads/stores (runtime sniff picks BF) ---------
template<bool BF> __device__ __forceinline__ float ld(const void* p, int i);
template<> __device__ __forceinline__ float ld<true>(const void* p, int i) {
    return __bfloat162float(((const __hip_bfloat16*)p)[i]);
}
template<> __device__ __forceinline__ float ld<false>(const void* p, int i) {
    return ((const float*)p)[i];
}
template<bool BF> __device__ __forceinline__ float2 ld2(const void* p, int i);
template<> __device__ __forceinline__ float2 ld2<false>(const void* p, int i) {
    return *(const float2*)((const float*)p + i);
}
template<> __device__ __forceinline__ float2 ld2<true>(const void* p, int i) {
    float2 r; r.x = ld<true>(p, i); r.y = ld<true>(p, i + 1); return r;
}
template<bool BF> __device__ __forceinline__ float4 ld4(const void* p, int i);
template<> __device__ __forceinline__ float4 ld4<false>(const void* p, int i) {
    return *(const float4*)((const float*)p + i);
}
template<> __device__ __forceinline__ float4 ld4<true>(const void* p, int i) {
    float4 r; r.x = ld<true>(p, i); r.y = ld<true>(p, i + 1);
    r.z = ld<true>(p, i + 2); r.w = ld<true>(p, i + 3); return r;
}
template<bool BF> __device__ __forceinline__ void st4(void* p, int i, float4 v);
template<> __device__ __forceinline__ void st4<true>(void* p, int i, float4 v) {
    __hip_bfloat16* o = (__hip_bfloat16*)p + i;
    o[0] = __float2bfloat16(v.x); o[1] = __float2bfloat16(v.y);
    o[2] = __float2bfloat16(v.z); o[3] = __float2bfloat16(v.w);
}
template<> __device__ __forceinline__ void st4<false>(void* p, int i, float4 v) {
    *(float4*)((float*)p + i) = v;
}

// ---------- dtype sniff: EVEN half-words of sorted-uniform ref_time ---------
__device__ __forceinline__ bool sniff_bf16(const void* ref_time) {
    const int lane = threadIdx.x & 63;
    bool ok = true;
    if (lane < 32) {
        float v = __bfloat162float(((const __hip_bfloat16*)ref_time)[2 * lane]);
        ok = (v >= 0.0f) && (v <= 1.0f);   // NaN fails
    }
    return __ballot(ok) == ~0ULL;
}

// ---------- binary searches ----------
__device__ int lb_int(const int* arr, int n, int key) {
    int lo = 0, hi = n;
    while (lo < hi) { int mid = (lo + hi) >> 1; if (arr[mid] < key) lo = mid + 1; else hi = mid; }
    return lo;
}
__device__ int ub_int(const int* arr, int n, int key) {
    int lo = 0, hi = n;
    while (lo < hi) { int mid = (lo + hi) >> 1; if (arr[mid] <= key) lo = mid + 1; else hi = mid; }
    return lo;
}

// ---------- prep part: alpha/beta linear in the ref row (verified R8-R10) ---
template<bool BF>
__device__ void prep_part(
    const void* ref_data, const void* ref_time, const int* ref_idx,
    const void* m1_time, const int* m1_idx, const void* m2_time, const int* m2_idx,
    const void* Wq, const void* bq,
    const void* Wk1, const void* bk1, const void* Wk2, const void* bk2,
    float* alpha1, float* beta1, float* alpha2, float* beta2,
    int* c1, int* s1, int* e1, int* c2, int* s2, int* e2)
{
    __shared__ float ut[64][4];
    __shared__ float cst[4];
    __shared__ int tabs[4][8];

    const int tid = threadIdx.x;    // 256
    const int i = tid >> 2, r = tid & 3;

    {
        const void* w = (r == 0) ? Wk1 : (r == 1) ? bk1 : (r == 2) ? Wk2 : bk2;
        const bool isA = (r & 1);
        float acc = isA ? ld<BF>(Wq, i * 128) : 0.0f;
        const float sgn = isA ? -1.0f : 1.0f;
        #pragma unroll 4
        for (int d = 1; d < 128; ++d)
            acc = fmaf(sgn * ld<BF>(Wq, i * 128 + d), ld<BF>(w, d - 1), acc);
        ut[i][r] = acc;
    }
    if (tid < 4) {
        const void* w = (tid == 0) ? Wk1 : (tid == 1) ? bk1 : (tid == 2) ? Wk2 : bk2;
        const bool isA = (tid & 1);
        float c = isA ? ld<BF>(bq, 0) : 0.0f;
        const float sgn = isA ? -1.0f : 1.0f;
        #pragma unroll 4
        for (int d = 1; d < 128; ++d)
            c = fmaf(sgn * ld<BF>(bq, d), ld<BF>(w, d - 1), c);
        c += sgn * ld<BF>(w, 127);
        cst[tid] = c;
    }
    if (tid >= 4 && tid < 36) {
        const int k = tid - 4;
        const int sid = k & 7, rest = k >> 3;
        const int modk = rest & 1, kind = rest >> 1;
        const int* arr = modk ? m2_idx : m1_idx;
        tabs[modk * 2 + kind][sid] = kind ? ub_int(arr, LK, sid) : lb_int(arr, LK, sid);
    }
    __syncthreads();

    const int q = tid & 127;
    const int t = blockIdx.x * PQ + q;
    if (tid < 128) {
        float4 acc = {cst[0], cst[1], cst[2], cst[3]};
        #pragma unroll
        for (int ii = 0; ii < 64; ii += 4) {
            const float4 rv = ld4<BF>(ref_data, t * 64 + ii);
            const float4 u0 = *(const float4*)ut[ii + 0];
            const float4 u1 = *(const float4*)ut[ii + 1];
            const float4 u2 = *(const float4*)ut[ii + 2];
            const float4 u3 = *(const float4*)ut[ii + 3];
            acc.x = fmaf(rv.x, u0.x, fmaf(rv.y, u1.x, fmaf(rv.z, u2.x, fmaf(rv.w, u3.x, acc.x))));
            acc.y = fmaf(rv.x, u0.y, fmaf(rv.y, u1.y, fmaf(rv.z, u2.y, fmaf(rv.w, u3.y, acc.y))));
            acc.z = fmaf(rv.x, u0.z, fmaf(rv.y, u1.z, fmaf(rv.z, u2.z, fmaf(rv.w, u3.z, acc.z))));
            acc.w = fmaf(rv.x, u0.w, fmaf(rv.y, u1.w, fmaf(rv.z, u2.w, fmaf(rv.w, u3.w, acc.w))));
        }
        beta1[t] = acc.x; alpha1[t] = acc.y;
        beta2[t] = acc.z; alpha2[t] = acc.w;
    } else {
        const float qt = ld<BF>(ref_time, t);
        const int g = ref_idx[t];
        int lo1 = 0, hi1 = LK, lo2 = 0, hi2 = LK;
        #pragma unroll
        for (int it = 0; it < 13; ++it) {
            const int mA = min((lo1 + hi1) >> 1, LK - 1);
            const int mB = min((lo2 + hi2) >> 1, LK - 1);
            const float v1 = ld<BF>(m1_time, mA);
            const float v2 = ld<BF>(m2_time, mB);
            if (lo1 < hi1) { if (v1 <= qt) lo1 = mA + 1; else hi1 = mA; }
            if (lo2 < hi2) { if (v2 <= qt) lo2 = mB + 1; else hi2 = mB; }
        }
        c1[t] = lo1; c2[t] = lo2;
        s1[t] = tabs[0][g]; e1[t] = tabs[1][g];
        s2[t] = tabs[2][g]; e2[t] = tabs[3][g];
    }
}

// ---------- vproj part: one wave per 4 rows, register-tiled, no LDS ---------
template<bool BF, int K, int DM>
__device__ void vproj_wave(const void* md, const void* Wv, const void* bv,
                           float* V, float* X, int rows0)
{
    const int lane = threadIdx.x & 63;
    const int cT = lane & 31;
    const int rG = lane >> 5;          // 0/1 -> rows rG*2..rG*2+1
    const int r0 = rows0 + rG * 2;
    const int c4 = cT * 4;

    const float4 bb = ld4<BF>(bv, c4);
    float4 acc[2] = {bb, bb};

    #pragma unroll 4
    for (int k = 0; k < K; k += 4) {
        const float4 w0 = ld4<BF>(Wv, (k + 0) * 128 + c4);
        const float4 w1 = ld4<BF>(Wv, (k + 1) * 128 + c4);
        const float4 w2 = ld4<BF>(Wv, (k + 2) * 128 + c4);
        const float4 w3 = ld4<BF>(Wv, (k + 3) * 128 + c4);
        float2 alo[2], ahi[2];
        #pragma unroll
        for (int r = 0; r < 2; ++r) {
            alo[r] = ld2<BF>(md, (r0 + r) * DM + k);
            ahi[r] = ld2<BF>(md, (r0 + r) * DM + k + 2);
        }
        #pragma unroll
        for (int r = 0; r < 2; ++r) {
            acc[r].x = fmaf(alo[r].x, w0.x, fmaf(alo[r].y, w1.x, fmaf(ahi[r].x, w2.x, fmaf(ahi[r].y, w3.x, acc[r].x))));
            acc[r].y = fmaf(alo[r].x, w0.y, fmaf(alo[r].y, w1.y, fmaf(ahi[r].x, w2.y, fmaf(ahi[r].y, w3.y, acc[r].y))));
            acc[r].z = fmaf(alo[r].x, w0.z, fmaf(alo[r].y, w1.z, fmaf(ahi[r].x, w2.z, fmaf(ahi[r].y, w3.z, acc[r].z))));
            acc[r].w = fmaf(alo[r].x, w0.w, fmaf(alo[r].y, w1.w, fmaf(ahi[r].x, w2.w, fmaf(ahi[r].y, w3.w, acc[r].w))));
        }
    }
    #pragma unroll
    for (int r = 0; r < 2; ++r)
        *(float4*)&V[(size_t)(r0 + r) * 128 + c4] = acc[r];
    if (rG == 0 && cT < 4)
        X[rows0 + cT] = ld<BF>(md, (rows0 + cT) * DM + DM - 1);
}

// ---------- fused prep+vproj (one launch) -----------------------------------
template<bool BF>
__device__ void pv_body(
    const void* ref_data, const void* ref_time, const int* ref_idx,
    const void* m1_data, const void* m1_time, const int* m1_idx,
    const void* m2_data, const void* m2_time, const int* m2_idx,
    const void* Wq, const void* bq,
    const void* Wk1, const void* bk1, const void* Wk2, const void* bk2,
    const void* Wv1, const void* bv1, const void* Wv2, const void* bv2,
    float* alpha1, float* beta1, float* alpha2, float* beta2,
    int* c1, int* s1, int* e1, int* c2, int* s2, int* e2,
    float* V1, float* V2, float* X1, float* X2)
{
    if (blockIdx.x < PB) {
        prep_part<BF>(ref_data, ref_time, ref_idx, m1_time, m1_idx, m2_time, m2_idx,
                      Wq, bq, Wk1, bk1, Wk2, bk2,
                      alpha1, beta1, alpha2, beta2, c1, s1, e1, c2, s2, e2);
    } else {
        const int vb = blockIdx.x - PB;          // 0..VPB-1
        const int mod = vb >> 8;                 // 256 blocks per modality
        const int wid = threadIdx.x >> 6;        // 4 waves x 4 rows = 16 rows/block
        const int rows0 = (vb & 255) * 16 + wid * 4;
        if (mod == 0) vproj_wave<BF, 128, 130>(m1_data, Wv1, bv1, V1, X1, rows0);
        else          vproj_wave<BF, 64, 66>(m2_data, Wv2, bv2, V2, X2, rows0);
    }
}

__global__ __launch_bounds__(256) void pv_kernel(
    const void* ref_data, const void* ref_time, const int* ref_idx,
    const void* m1_data, const void* m1_time, const int* m1_idx,
    const void* m2_data, const void* m2_time, const int* m2_idx,
    const void* Wq, const void* bq,
    const void* Wk1, const void* bk1, const void* Wk2, const void* bk2,
    const void* Wv1, const void* bv1, const void* Wv2, const void* bv2,
    float* alpha1, float* beta1, float* alpha2, float* beta2,
    int* c1, int* s1, int* e1, int* c2, int* s2, int* e2,
    float* V1, float* V2, float* X1, float* X2)
{
    if (sniff_bf16(ref_time))
        pv_body<true>(ref_data, ref_time, ref_idx, m1_data, m1_time, m1_idx,
                      m2_data, m2_time, m2_idx, Wq, bq, Wk1, bk1, Wk2, bk2,
                      Wv1, bv1, Wv2, bv2, alpha1, beta1, alpha2, beta2,
                      c1, s1, e1, c2, s2, e2, V1, V2, X1, X2);
    else
        pv_body<false>(ref_data, ref_time, ref_idx, m1_data, m1_time, m1_idx,
                       m2_data, m2_time, m2_idx, Wq, bq, Wk1, bk1, Wk2, bk2,
                       Wv1, bv1, Wv2, bv2, alpha1, beta1, alpha2, beta2,
                       c1, s1, e1, c2, s2, e2, V1, V2, X1, X2);
}

// ---------- attn v8: single block per (tile,mod), 8 independent waves,
// barrier-free inner loops, ONE barrier + LDS merge, direct output write. ----
__global__ __launch_bounds__(512) void attn_kernel(
    const void* __restrict__ ref_time,
    const float* __restrict__ alpha1, const float* __restrict__ beta1,
    const float* __restrict__ alpha2, const float* __restrict__ beta2,
    const int* __restrict__ c1, const int* __restrict__ s1, const int* __restrict__ e1,
    const int* __restrict__ c2, const int* __restrict__ s2, const int* __restrict__ e2,
    const float* __restrict__ V1, const float* __restrict__ V2,
    const float* __restrict__ X1, const float* __restrict__ X2,
    const void* log_tau1, const void* log_tau2, void* __restrict__ out)
{
    __shared__ float sW[NW][CHJ * QT];   // per-wave w-tile [j][q]  (8 KB)
    __shared__ float sO[NW][QT * 128];   // per-wave O partial      (64 KB)
    __shared__ float sZ[NW][QT];         // per-wave Z partial

    const int tid = threadIdx.x;         // 512
    const int wid = tid >> 6, lane = tid & 63;
    const int t0 = blockIdx.x * QT, mod = blockIdx.y;

    const bool bf = sniff_bf16(ref_time);
    const float* alpha = mod ? alpha2 : alpha1;
    const float* beta  = mod ? beta2  : beta1;
    const int* cA = mod ? c2 : c1;
    const int* sA = mod ? s2 : s1;
    const int* eA = mod ? e2 : e1;
    const float* V = mod ? V2 : V1;
    const float* X = mod ? X2 : X1;
    const void* ltp = mod ? log_tau2 : log_tau1;
    const float scale = __expf(-(bf ? ld<true>(ltp, 0) : ld<false>(ltp, 0)));

    const int q = lane & 15;
    const int t = t0 + q;
    int s = sA[t], e = eA[t];
    const int c = cA[t];
    if (s == e) { s = 0; e = LK; }        // fully-masked fallback
    const int cm = min(c, e);             // causal&matched: [s, cm)
    const float al = alpha[t], be = beta[t];

    // tile union range via wave reduce (identical result in every wave)
    int es = (cm > s) ? s : 0x7fffffff;
    int ec = (cm > s) ? cm : 0;
    #pragma unroll
    for (int o = 1; o < 64; o <<= 1) {
        es = min(es, __shfl_xor(es, o));
        ec = max(ec, __shfl_xor(ec, o));
    }
    int jlo = es, jhi = ec;
    if (jlo > jhi) { jlo = 0; jhi = 0; }
    const int W = jhi - jlo;
    const int chunk = (W + NW - 1) / NW;
    const int lo = jlo + wid * chunk;
    int hi = min(jhi, lo + chunk); if (hi < lo) hi = lo;

    const int cT = lane & 31, qG = lane >> 5;
    const int jj = lane >> 4;               // 0..3 -> j-slots jj*4..jj*4+3
    float4 acc[8] = {{0,0,0,0},{0,0,0,0},{0,0,0,0},{0,0,0,0},
                     {0,0,0,0},{0,0,0,0},{0,0,0,0},{0,0,0,0}};
    float zacc = 0.0f;
    float* myW = sW[wid];
    const float4* __restrict__ Vg = (const float4*)V;

    for (int base = lo; base < hi; base += CHJ) {
        const int jm = min(CHJ, hi - base);
        // drain prior chunk's ds_reads before overwriting this wave's tile
        __asm__ volatile("s_waitcnt lgkmcnt(0)" ::: "memory");
        #pragma unroll
        for (int p = 0; p < 4; ++p) {
            const int jr = jj * 4 + p;      // 0..15, full tile coverage
            const int j = base + jr;
            const bool ok = (jr < jm) && (j >= s) && (j < cm);
            const float x = X[min(j, LK - 1)];
            const float qk = fmaf(-be, x, al);
            const float w = ok ? __expf(-(qk * qk) * scale) : 0.0f;
            myW[jr * QT + q] = w;
            zacc += w;
        }
        // make this wave's LDS writes visible to all its lanes (lockstep wave)
        __asm__ volatile("s_waitcnt lgkmcnt(0)" ::: "memory");
        #pragma unroll 4
        for (int j = 0; j < jm; ++j) {
            const float4 v = Vg[(base + j) * 32 + cT];
            const float4* wv = (const float4*)&myW[j * QT + qG * 8];
            const float4 wA = wv[0], wB = wv[1];
            acc[0].x = fmaf(wA.x, v.x, acc[0].x); acc[0].y = fmaf(wA.x, v.y, acc[0].y);
            acc[0].z = fmaf(wA.x, v.z, acc[0].z); acc[0].w = fmaf(wA.x, v.w, acc[0].w);
            acc[1].x = fmaf(wA.y, v.x, acc[1].x); acc[1].y = fmaf(wA.y, v.y, acc[1].y);
            acc[1].z = fmaf(wA.y, v.z, acc[1].z); acc[1].w = fmaf(wA.y, v.w, acc[1].w);
            acc[2].x = fmaf(wA.z, v.x, acc[2].x); acc[2].y = fmaf(wA.z, v.y, acc[2].y);
            acc[2].z = fmaf(wA.z, v.z, acc[2].z); acc[2].w = fmaf(wA.z, v.w, acc[2].w);
            acc[3].x = fmaf(wA.w, v.x, acc[3].x); acc[3].y = fmaf(wA.w, v.y, acc[3].y);
            acc[3].z = fmaf(wA.w, v.z, acc[3].z); acc[3].w = fmaf(wA.w, v.w, acc[3].w);
            acc[4].x = fmaf(wB.x, v.x, acc[4].x); acc[4].y = fmaf(wB.x, v.y, acc[4].y);
            acc[4].z = fmaf(wB.x, v.z, acc[4].z); acc[4].w = fmaf(wB.x, v.w, acc[4].w);
            acc[5].x = fmaf(wB.y, v.x, acc[5].x); acc[5].y = fmaf(wB.y, v.y, acc[5].y);
            acc[5].z = fmaf(wB.y, v.z, acc[5].z); acc[5].w = fmaf(wB.y, v.w, acc[5].w);
            acc[6].x = fmaf(wB.z, v.x, acc[6].x); acc[6].y = fmaf(wB.z, v.y, acc[6].y);
            acc[6].z = fmaf(wB.z, v.z, acc[6].z); acc[6].w = fmaf(wB.z, v.w, acc[6].w);
            acc[7].x = fmaf(wB.w, v.x, acc[7].x); acc[7].y = fmaf(wB.w, v.y, acc[7].y);
            acc[7].z = fmaf(wB.w, v.z, acc[7].z); acc[7].w = fmaf(wB.w, v.w, acc[7].w);
        }
    }

    // per-wave z reduce over the 4 lanes sharing this q
    float z = zacc;
    z += __shfl_xor(z, 16);
    z += __shfl_xor(z, 32);

    // deposit partials; ONE barrier; merge + normalize + store.
    #pragma unroll
    for (int r = 0; r < 8; ++r)
        *(float4*)&sO[wid][(qG * 8 + r) * 128 + cT * 4] = acc[r];
    if (lane < 16) sZ[wid][lane] = z;
    __syncthreads();

    // merge phase: 512 threads x 1 float4 = 16q x 128 cols
    const int mq = tid >> 5, mc = tid & 31;
    const int mt = t0 + mq;
    int ms = sA[mt], me = eA[mt];
    const int mcau = cA[mt];
    if (ms == me) { ms = 0; me = LK; }
    const int mnnc = (me > mcau) ? (me - max(ms, mcau)) : 0;

    float Z = (float)mnnc;
    float4 o = {0, 0, 0, 0};
    #pragma unroll
    for (int w = 0; w < NW; ++w) {
        Z += sZ[w][mq];
        const float4 p = *(const float4*)&sO[w][mq * 128 + mc * 4];
        o.x += p.x; o.y += p.y; o.z += p.z; o.w += p.w;
    }
    const float inv = 1.0f / fmaxf(Z, 1.0e-20f);
    o.x *= inv; o.y *= inv; o.z *= inv; o.w *= inv;
    if (bf) st4<true>(out, mt * 256 + mod * 128 + mc * 4, o);
    else    st4<false>(out, mt * 256 + mod * 128 + mc * 4, o);
}

extern "C" void kernel_launch(void* const* d_in, const int* in_sizes, int n_in,
                              void* d_out, int out_size, void* d_ws, size_t ws_size,
                              hipStream_t stream)
{
    const void* ref_data = d_in[0];
    const void* ref_time = d_in[1];
    const int*  ref_idx  = (const int*)d_in[2];
    const void* m1_data  = d_in[3];
    const void* m1_time  = d_in[4];
    const int*  m1_idx   = (const int*)d_in[5];
    const void* m2_data  = d_in[6];
    const void* m2_time  = d_in[7];
    const int*  m2_idx   = (const int*)d_in[8];
    const void* Wq  = d_in[9];
    const void* bq  = d_in[10];
    const void* Wk1 = d_in[11];
    const void* bk1 = d_in[12];
    const void* Wv1 = d_in[13];
    const void* bv1 = d_in[14];
    const void* Wk2 = d_in[15];
    const void* bk2 = d_in[16];
    const void* Wv2 = d_in[17];
    const void* bv2 = d_in[18];
    const void* log_tau1 = d_in[19];
    const void* log_tau2 = d_in[20];

    float* ws = (float*)d_ws;
    float* alpha1 = ws + 0 * TQ;
    float* beta1  = ws + 1 * TQ;
    float* alpha2 = ws + 2 * TQ;
    float* beta2  = ws + 3 * TQ;
    int*   c1 = (int*)(ws + 4 * TQ);
    int*   c2 = (int*)(ws + 5 * TQ);
    int*   s1 = (int*)(ws + 6 * TQ);
    int*   e1 = (int*)(ws + 7 * TQ);
    int*   s2 = (int*)(ws + 8 * TQ);
    int*   e2 = (int*)(ws + 9 * TQ);
    float* X1 = ws + 10 * TQ;
    float* X2 = ws + 11 * TQ;
    float* V1 = ws + 12 * TQ;                      // LK*128 floats
    float* V2 = V1 + (size_t)LK * 128;

    pv_kernel<<<dim3(PB + VPB), dim3(256), 0, stream>>>(
        ref_data, ref_time, ref_idx, m1_data, m1_time, m1_idx,
        m2_data, m2_time, m2_idx, Wq, bq, Wk1, bk1, Wk2, bk2,
        Wv1, bv1, Wv2, bv2, alpha1, beta1, alpha2, beta2,
        c1, s1, e1, c2, s2, e2, V1, V2, X1, X2);

    attn_kernel<<<dim3(TQ / QT, 2), dim3(512), 0, stream>>>(
        ref_time, alpha1, beta1, alpha2, beta2, c1, s1, e1, c2, s2, e2,
        V1, V2, X1, X2, log_tau1, log_tau2, (void*)d_out);
}